// Round 6
// baseline (445.718 us; speedup 1.0000x reference)
//
#include <hip/hip_runtime.h>
#include <hip/hip_bf16.h>
#include <stdint.h>

typedef __attribute__((ext_vector_type(8))) short bf16x8;
typedef __attribute__((ext_vector_type(4))) float f32x4;
typedef __attribute__((ext_vector_type(4))) unsigned short us4;
typedef __attribute__((ext_vector_type(8))) unsigned short us8;

__device__ __forceinline__ unsigned short f2bf(float f) {
  union { float f; unsigned int u; } v; v.f = f;
  unsigned int u = v.u;
  return (unsigned short)((u + 0x7FFFu + ((u >> 16) & 1u)) >> 16);
}
__device__ __forceinline__ float bf2f(unsigned short h) {
  union { unsigned int u; float f; } v; v.u = ((unsigned int)h) << 16;
  return v.f;
}

// async global->LDS, 16B per lane; LDS dest = wave-uniform base + lane*16
__device__ __forceinline__ void gload16(const unsigned short* g, unsigned short* l) {
  __builtin_amdgcn_global_load_lds(
      (const __attribute__((address_space(1))) unsigned int*)g,
      (__attribute__((address_space(3))) unsigned int*)l, 16, 0, 0);
}

// ---------------------------------------------------------------------------
// 256x256 tile NT GEMM, BK=64, 512 threads (8 waves), counted-vmcnt pipeline.
// C[M,N] = A[M,K] * Bt[N,K]^T, A/B bf16 row-major (lda=ldb=K).
// LDS: 2 buffers x 4 halves (A0,A1,B0,B1), each 128x64 bf16 = 16KB -> 128KiB.
// Staging: global_load_lds w16, pre-swizzled source (slot s -> s^(r&7));
// reads apply the same XOR -> conflict-free, zero staging VALU.
// Schedule per K-tile t (quadrants (ha,hb)): each phase
//   vmcnt(4); s_barrier; sched_barrier; issue next-tile half; ds_read; MFMA
// vmcnt(4): the 4 newest outstanding loads are exactly the not-yet-needed
// halves -> consumed halves complete. Issue-after-barrier: all waves past the
// barrier => prior-quadrant ds_reads drained (their MFMAs waited lgkmcnt).
// EPI 0: bf16 C row-major          EPI 1: scores (thr+exp, bf16 e + partials)
// EPI 2: bf16 C transposed per batch (v-proj)   EPI 3: bf16 acc*inv[row] (PV)
// ---------------------------------------------------------------------------
template <int EPI>
__global__ __launch_bounds__(512, 2)
void gemm8(const unsigned short* __restrict__ Ap, const unsigned short* __restrict__ Btp,
           void* __restrict__ Cp, float* __restrict__ extra,
           int M, int N, int K, int nbm, int nbn,
           long long sA, long long sB, long long sC)
{
  __shared__ unsigned short ls[65536];    // 128 KiB: [buf][A0|A1|B0|B1][128][64]
  __shared__ float srow[256][4];

  const int tid = threadIdx.x;
  const int lane = tid & 63;
  const int wid = tid >> 6;
  const int bb = blockIdx.y;
  const int bm = blockIdx.x % nbm, bn = blockIdx.x / nbm;
  const int row0 = bm * 256, col0 = bn * 256;

  const unsigned short* Ab = Ap + (long long)bb * sA;
  const unsigned short* Bb = Btp + (long long)bb * sB;

  // staging: thread covers row sr (0..63 per 64-row chunk), slot pre-swizzled
  const int sr = tid >> 3;
  const int sslot = (tid & 7) ^ (sr & 7);
  const unsigned short* Asrc = Ab + (long long)(row0 + sr) * K + sslot * 8;
  const unsigned short* Bsrc = Bb + (long long)(col0 + sr) * K + sslot * 8;
  unsigned short* lsw = ls + wid * 512;   // wave-uniform LDS slice base

#define ISSUE_A(HALF, BUFOFF, KOFF) do { \
    gload16(Asrc + (long long)((HALF) * 128) * K + (KOFF), lsw + (BUFOFF) + (HALF) * 8192); \
    gload16(Asrc + (long long)((HALF) * 128 + 64) * K + (KOFF), lsw + (BUFOFF) + (HALF) * 8192 + 4096); \
  } while (0)
#define ISSUE_B(HALF, BUFOFF, KOFF) do { \
    gload16(Bsrc + (long long)((HALF) * 128) * K + (KOFF), lsw + (BUFOFF) + (2 + (HALF)) * 8192); \
    gload16(Bsrc + (long long)((HALF) * 128 + 64) * K + (KOFF), lsw + (BUFOFF) + (2 + (HALF)) * 8192 + 4096); \
  } while (0)

  const int warow = ((wid >> 2) * 64) + (lane & 15);   // A row within half
  const int wbcol = ((wid & 3) * 32) + (lane & 15);    // B col within half

  f32x4 acc[2][2][4][2];
#pragma unroll
  for (int a = 0; a < 2; ++a)
#pragma unroll
    for (int b = 0; b < 2; ++b)
#pragma unroll
      for (int m = 0; m < 4; ++m)
#pragma unroll
        for (int n = 0; n < 2; ++n) {
          f32x4 z = {0.f, 0.f, 0.f, 0.f};
          acc[a][b][m][n] = z;
        }

#define PHASE(HA, HB) do { \
    const unsigned short* Ah = ls + cur + (HA) * 8192; \
    const unsigned short* Bh = ls + cur + (2 + (HB)) * 8192; \
    _Pragma("unroll") \
    for (int kk = 0; kk < 2; ++kk) { \
      const int kslot = kk * 4 + (lane >> 4); \
      bf16x8 af[4], bfr[2]; \
      _Pragma("unroll") \
      for (int mf = 0; mf < 4; ++mf) { \
        const int rl = warow + mf * 16; \
        af[mf] = *(const bf16x8*)&Ah[rl * 64 + ((kslot ^ (rl & 7)) * 8)]; \
      } \
      _Pragma("unroll") \
      for (int nf = 0; nf < 2; ++nf) { \
        const int cl = wbcol + nf * 16; \
        bfr[nf] = *(const bf16x8*)&Bh[cl * 64 + ((kslot ^ (cl & 7)) * 8)]; \
      } \
      __builtin_amdgcn_s_setprio(1); \
      _Pragma("unroll") \
      for (int mf = 0; mf < 4; ++mf) \
        _Pragma("unroll") \
        for (int nf = 0; nf < 2; ++nf) \
          acc[HA][HB][mf][nf] = __builtin_amdgcn_mfma_f32_16x16x32_bf16( \
              af[mf], bfr[nf], acc[HA][HB][mf][nf], 0, 0, 0); \
      __builtin_amdgcn_s_setprio(0); \
    } \
  } while (0)

#define WAITBAR() do { \
    asm volatile("s_waitcnt vmcnt(4)" ::: "memory"); \
    __builtin_amdgcn_s_barrier(); \
    __builtin_amdgcn_sched_barrier(0); \
  } while (0)

  // prologue: tile 0 halves, FIFO order A0,B0,A1,B1 -> buf0
  ISSUE_A(0, 0, 0);
  ISSUE_B(0, 0, 0);
  ISSUE_A(1, 0, 0);
  ISSUE_B(1, 0, 0);

  const int NT = K >> 6;
  for (int t = 0; t < NT; ++t) {
    const int cur = (t & 1) << 15;
    const int nxt = ((t + 1) & 1) << 15;
    const long long ko = (long long)(t + 1) * 64;
    const bool pf = (t + 1 < NT);
    WAITBAR();                       // guarantees A0(t),B0(t) landed
    if (pf) ISSUE_A(0, nxt, ko);
    PHASE(0, 0);
    WAITBAR();                       // guarantees A1(t) (and B1(t)) landed
    if (pf) ISSUE_B(0, nxt, ko);
    PHASE(1, 0);
    WAITBAR();                       // B1(t) (usually already retired)
    if (pf) ISSUE_A(1, nxt, ko);
    PHASE(0, 1);
    if (pf) ISSUE_B(1, nxt, ko);     // no wait/barrier needed for (1,1)
    PHASE(1, 1);
  }

  // ---------------- epilogues ----------------
  if (EPI == 0 || EPI == 3) {
    unsigned short* C = (unsigned short*)Cp + (long long)bb * sC;
    const float* inv = (EPI == 3) ? (extra + (long long)bb * 2048) : nullptr;
#pragma unroll
    for (int ha = 0; ha < 2; ++ha)
#pragma unroll
      for (int hb = 0; hb < 2; ++hb)
#pragma unroll
        for (int mf = 0; mf < 4; ++mf)
#pragma unroll
          for (int nf = 0; nf < 2; ++nf)
#pragma unroll
            for (int i = 0; i < 4; ++i) {
              int gr = row0 + ha * 128 + (wid >> 2) * 64 + mf * 16 + (lane >> 4) * 4 + i;
              int gc = col0 + hb * 128 + (wid & 3) * 32 + nf * 16 + (lane & 15);
              float x = acc[ha][hb][mf][nf][i];
              if (EPI == 3) x *= inv[gr];
              C[(long long)gr * N + gc] = f2bf(x);
            }
  } else if (EPI == 2) {
    unsigned short* C = (unsigned short*)Cp;
#pragma unroll
    for (int ha = 0; ha < 2; ++ha)
#pragma unroll
      for (int hb = 0; hb < 2; ++hb)
#pragma unroll
        for (int mf = 0; mf < 4; ++mf)
#pragma unroll
          for (int nf = 0; nf < 2; ++nf) {
            int gr = row0 + ha * 128 + (wid >> 2) * 64 + mf * 16 + (lane >> 4) * 4;
            int gc = col0 + hb * 128 + (wid & 3) * 32 + nf * 16 + (lane & 15);
            int bb2 = gr >> 11, grb = gr & 2047;
            us4 o;
            o[0] = f2bf(acc[ha][hb][mf][nf][0]); o[1] = f2bf(acc[ha][hb][mf][nf][1]);
            o[2] = f2bf(acc[ha][hb][mf][nf][2]); o[3] = f2bf(acc[ha][hb][mf][nf][3]);
            *(us4*)&C[(long long)bb2 * sC + (long long)gc * 2048 + grb] = o;
          }
  } else {   // EPI 1: scores
    unsigned short* C = (unsigned short*)Cp + (long long)bb * sC;
    float rs[2][4][4];
#pragma unroll
    for (int ha = 0; ha < 2; ++ha)
#pragma unroll
      for (int mf = 0; mf < 4; ++mf)
#pragma unroll
        for (int i = 0; i < 4; ++i) rs[ha][mf][i] = 0.f;
#pragma unroll
    for (int ha = 0; ha < 2; ++ha)
#pragma unroll
      for (int hb = 0; hb < 2; ++hb)
#pragma unroll
        for (int mf = 0; mf < 4; ++mf)
#pragma unroll
          for (int nf = 0; nf < 2; ++nf)
#pragma unroll
            for (int i = 0; i < 4; ++i) {
              int gr = row0 + ha * 128 + (wid >> 2) * 64 + mf * 16 + (lane >> 4) * 4 + i;
              int gc = col0 + hb * 128 + (wid & 3) * 32 + nf * 16 + (lane & 15);
              float s = acc[ha][hb][mf][nf][i] * 0.03125f;   // 1/sqrt(1024)
              s = (s < 0.9f) ? 0.f : s;                      // threshold pre-softmax
              float e = __expf(s);                           // bounded: no max-sub
              C[(long long)gr * N + gc] = f2bf(e);
              rs[ha][mf][i] += e;
            }
#pragma unroll
    for (int ha = 0; ha < 2; ++ha)
#pragma unroll
      for (int mf = 0; mf < 4; ++mf)
#pragma unroll
        for (int i = 0; i < 4; ++i) {
          float vv = rs[ha][mf][i];
          vv += __shfl_xor(vv, 1); vv += __shfl_xor(vv, 2);
          vv += __shfl_xor(vv, 4); vv += __shfl_xor(vv, 8);
          if ((lane & 15) == 0)
            srow[ha * 128 + (wid >> 2) * 64 + mf * 16 + (lane >> 4) * 4 + i][wid & 3] = vv;
        }
    __syncthreads();
    if (tid < 256) {
      int gr = row0 + tid;
      extra[((long long)bb * M + gr) * nbn + bn] =
          srow[tid][0] + srow[tid][1] + srow[tid][2] + srow[tid][3];
    }
  }
#undef PHASE
#undef WAITBAR
#undef ISSUE_A
#undef ISSUE_B
}

// ---------------------------------------------------------------------------
// q,k,v fp32 -> bf16, one pass (8 elem/thread each)
// ---------------------------------------------------------------------------
__global__ __launch_bounds__(256)
void cvt3(const float* __restrict__ a, const float* __restrict__ b,
          const float* __restrict__ c, unsigned short* __restrict__ oa,
          unsigned short* __restrict__ ob, unsigned short* __restrict__ oc) {
  const long long i = ((long long)blockIdx.x * 256 + threadIdx.x) * 8;
#pragma unroll
  for (int p = 0; p < 3; ++p) {
    const float* src = (p == 0) ? a : (p == 1) ? b : c;
    unsigned short* dst = (p == 0) ? oa : (p == 1) ? ob : oc;
    f32x4 x0 = *(const f32x4*)(src + i);
    f32x4 x1 = *(const f32x4*)(src + i + 4);
    us8 o;
    o[0] = f2bf(x0[0]); o[1] = f2bf(x0[1]); o[2] = f2bf(x0[2]); o[3] = f2bf(x0[3]);
    o[4] = f2bf(x1[0]); o[5] = f2bf(x1[1]); o[6] = f2bf(x1[2]); o[7] = f2bf(x1[3]);
    *(us8*)(dst + i) = o;
  }
}

// ---------------------------------------------------------------------------
// W [1024][1024] fp32 -> WT [1024][1024] bf16 (transposed)
// ---------------------------------------------------------------------------
__global__ __launch_bounds__(256)
void wtrans(const float* __restrict__ W, unsigned short* __restrict__ WT) {
  __shared__ float t[32][33];
  const int bi = blockIdx.x, bj = blockIdx.y;
  const int c = threadIdx.x & 31;
  const int r0 = threadIdx.x >> 5;
#pragma unroll
  for (int j = 0; j < 4; ++j) {
    int r = r0 + j * 8;
    t[r][c] = W[(long long)(bi * 32 + r) * 1024 + bj * 32 + c];
  }
  __syncthreads();
#pragma unroll
  for (int j = 0; j < 4; ++j) {
    int r = r0 + j * 8;
    WT[(long long)(bj * 32 + r) * 1024 + bi * 32 + c] = f2bf(t[c][r]);
  }
}

// ---------------------------------------------------------------------------
// attn f32 output + inv_dens from bf16 exp-scores and partials (width 8)
// ---------------------------------------------------------------------------
__global__ __launch_bounds__(256)
void attn_norm(const unsigned short* __restrict__ e, const float* __restrict__ partials,
               float* __restrict__ attn, float* __restrict__ inv_dens) {
  const long long row = blockIdx.x;
  const int tid = threadIdx.x;
  __shared__ float sden;
  if (tid < 64) {
    float v = (tid < 8) ? partials[row * 8 + tid] : 0.f;
    v += __shfl_xor(v, 1); v += __shfl_xor(v, 2); v += __shfl_xor(v, 4);
    if (tid == 0) sden = v;
  }
  __syncthreads();
  const float inv = 1.0f / sden;
  if (tid == 0) inv_dens[row] = inv;
  us8 x = *(const us8*)(e + row * 2048 + tid * 8);
  f32x4 y0, y1;
#pragma unroll
  for (int i = 0; i < 4; ++i) { y0[i] = bf2f(x[i]) * inv; y1[i] = bf2f(x[i + 4]) * inv; }
  *(f32x4*)(attn + row * 2048 + tid * 8) = y0;
  *(f32x4*)(attn + row * 2048 + tid * 8 + 4) = y1;
}

// ---------------------------------------------------------------------------
// out(f32) = LayerNorm(fc(bf16) + q(f32)) * gamma + beta   (row = 1024)
// ---------------------------------------------------------------------------
__global__ __launch_bounds__(256)
void ln_kernel(const unsigned short* __restrict__ fc, const float* __restrict__ q,
               const float* __restrict__ gamma, const float* __restrict__ beta,
               float* __restrict__ out) {
  const long long row = blockIdx.x;
  const int tid = threadIdx.x;
  __shared__ float sb1[4], sb2[4];
  us4 hv = *(const us4*)(fc + row * 1024 + tid * 4);
  f32x4 qv = *(const f32x4*)(q + row * 1024 + tid * 4);
  float x0 = bf2f(hv[0]) + qv[0];
  float x1 = bf2f(hv[1]) + qv[1];
  float x2 = bf2f(hv[2]) + qv[2];
  float x3 = bf2f(hv[3]) + qv[3];
  float s = x0 + x1 + x2 + x3;
#pragma unroll
  for (int m = 1; m < 64; m <<= 1) s += __shfl_xor(s, m);
  if ((tid & 63) == 0) sb1[tid >> 6] = s;
  __syncthreads();
  const float mean = (sb1[0] + sb1[1] + sb1[2] + sb1[3]) * (1.0f / 1024.0f);
  float d0 = x0 - mean, d1 = x1 - mean, d2 = x2 - mean, d3 = x3 - mean;
  float vs = d0 * d0 + d1 * d1 + d2 * d2 + d3 * d3;
#pragma unroll
  for (int m = 1; m < 64; m <<= 1) vs += __shfl_xor(vs, m);
  if ((tid & 63) == 0) sb2[tid >> 6] = vs;
  __syncthreads();
  const float var = (sb2[0] + sb2[1] + sb2[2] + sb2[3]) * (1.0f / 1024.0f);
  const float r = rsqrtf(var + 1e-6f);
  f32x4 g = *(const f32x4*)(gamma + tid * 4);
  f32x4 bt = *(const f32x4*)(beta + tid * 4);
  f32x4 o;
  o[0] = d0 * r * g[0] + bt[0];
  o[1] = d1 * r * g[1] + bt[1];
  o[2] = d2 * r * g[2] + bt[2];
  o[3] = d3 * r * g[3] + bt[3];
  *(f32x4*)(out + row * 1024 + tid * 4) = o;
}

// ---------------------------------------------------------------------------
// d_out = [ out0 f32 64MB | attn f32 128MB ].  Scratch timeline identical to
// round 5 (see comments there). ws: W*T @0/2/4/6M; partials@8M (512KB, w=8);
// inv_dens@10M; e bf16 @11M (64MB); fc reuses e after PV.
// ---------------------------------------------------------------------------
extern "C" void kernel_launch(void* const* d_in, const int* in_sizes, int n_in,
                              void* d_out, int out_size, void* d_ws, size_t ws_size,
                              hipStream_t stream) {
  const float* q    = (const float*)d_in[0];
  const float* k    = (const float*)d_in[1];
  const float* v    = (const float*)d_in[2];
  const float* Wq   = (const float*)d_in[3];
  const float* Wk   = (const float*)d_in[4];
  const float* Wv   = (const float*)d_in[5];
  const float* Wfc  = (const float*)d_in[6];
  const float* gamma = (const float*)d_in[7];
  const float* beta  = (const float*)d_in[8];

  float* out0 = (float*)d_out;
  float* attn = out0 + (long long)8 * 2048 * 1024;

  char* ao = (char*)attn;
  unsigned short* qb = (unsigned short*)(ao);
  unsigned short* kb = (unsigned short*)(ao + (32ll << 20));
  unsigned short* vb = (unsigned short*)(ao + (64ll << 20));
  unsigned short* qh = (unsigned short*)(ao + (96ll << 20));
  unsigned short* kh = (unsigned short*)(ao);
  unsigned short* vhT     = (unsigned short*)d_out;
  unsigned short* out_mid = (unsigned short*)((char*)d_out + (32ll << 20));

  char* ws = (char*)d_ws;
  unsigned short* WqT  = (unsigned short*)(ws);
  unsigned short* WkT  = (unsigned short*)(ws + (2ll  << 20));
  unsigned short* WvT  = (unsigned short*)(ws + (4ll  << 20));
  unsigned short* WfcT = (unsigned short*)(ws + (6ll  << 20));
  float* partials      = (float*)(ws + (8ll  << 20));            // [16384][8]
  float* inv_dens      = (float*)(ws + (10ll << 20));            // [16384]
  unsigned short* e    = (unsigned short*)(ws + (11ll << 20));   // 64MB
  unsigned short* fc   = e;

  // 1. conversions
  cvt3<<<dim3(8192), 256, 0, stream>>>(q, k, v, qb, kb, vb);
  wtrans<<<dim3(32, 32), 256, 0, stream>>>(Wq, WqT);
  wtrans<<<dim3(32, 32), 256, 0, stream>>>(Wk, WkT);
  wtrans<<<dim3(32, 32), 256, 0, stream>>>(Wv, WvT);
  wtrans<<<dim3(32, 32), 256, 0, stream>>>(Wfc, WfcT);

  // 2. projections (M=16384 batch-folded, 256x256 tiles: nbm=64, nbn=4)
  gemm8<0><<<dim3(256, 1), 512, 0, stream>>>(qb, WqT, qh, nullptr,
      16384, 1024, 1024, 64, 4, 0, 0, 0);
  gemm8<0><<<dim3(256, 1), 512, 0, stream>>>(kb, WkT, kh, nullptr,
      16384, 1024, 1024, 64, 4, 0, 0, 0);
  gemm8<2><<<dim3(256, 1), 512, 0, stream>>>(vb, WvT, vhT, nullptr,
      16384, 1024, 1024, 64, 4, 0, 0, 1024ll * 2048);   // vhT[b][d][s]

  // 3. scores: e = exp(thresh(qh kh^T / 32)) bf16 + partial row sums (w=8)
  gemm8<1><<<dim3(64, 8), 512, 0, stream>>>(qh, kh, e, partials,
      2048, 2048, 1024, 8, 8, 2048ll * 1024, 2048ll * 1024, 2048ll * 2048);

  // 4. attn(f32) = e/den; inv_dens
  attn_norm<<<dim3(16384), 256, 0, stream>>>(e, partials, attn, inv_dens);

  // 5. PV: out_mid = (e @ vh) * inv_den[row]   (nbm=8, nbn=4)
  gemm8<3><<<dim3(32, 8), 512, 0, stream>>>(e, vhT, out_mid, inv_dens,
      2048, 1024, 2048, 8, 4, 2048ll * 2048, 1024ll * 2048, 2048ll * 1024);

  // 6. FC: fc = out_mid @ Wfc
  gemm8<0><<<dim3(256, 1), 512, 0, stream>>>(out_mid, WfcT, fc, nullptr,
      16384, 1024, 1024, 64, 4, 0, 0, 0);

  // 7. out0 = LN(fc + q)
  ln_kernel<<<dim3(16384), 256, 0, stream>>>(fc, q, gamma, beta, out0);
}